// Round 8
// baseline (5203.353 us; speedup 1.0000x reference)
//
#include <hip/hip_runtime.h>
#include <math.h>

#define B 128
#define S 512
#define E 128
#define R 256

#define NG 32      // groups (each owns 4 batch elements)
#define QW 8       // wgs per group
#define ELS 4      // batch elements per group
#define OUTS 128   // gate-outputs per wg = 4 gates x 32 units

typedef float v2f __attribute__((ext_vector_type(2)));

// ---- workspace layout (float offsets) ----
static const size_t HX_OFF   = 0;                              // HX: [2][B][R] exchange buf
static const size_t SYNC_OFF = HX_OFF + 2ull * B * R;          // 1024 ints
static const size_t XG_OFF   = SYNC_OFF + 1024;                // Xg: [S][E/4][B][4]
static const size_t HS_OFF   = XG_OFF + (size_t)S * E * B;     // HS: [S][B][R]
static const size_t WUT_OFF  = HS_OFF + (size_t)S * B * R;     // WUt: [1024][384]
static const size_t WS_FLOATS = WUT_OFF + 1024ull * 384;       // ~102.5 MB

// output: probs [B][S][9] ; h_last [B][R] ; c_last [B][R]
#define HOUT_OFF 589824
#define COUT_OFF 622592

__global__ void zero_sync(int* __restrict__ sync) {
    sync[threadIdx.x] = 0;   // 1024 threads
}

// X4[t][e4][b] = embed[idx[b][t]][e4]   (float4 granularity, b contiguous)
__global__ void gather_x(const int* __restrict__ idx, const float* __restrict__ embed,
                         float4* __restrict__ X4) {
    int t    = blockIdx.x;
    int tid  = threadIdx.x;          // 256
    int b    = tid & 127;
    int half = tid >> 7;
    int row  = idx[(size_t)b * S + t];
    const float4* er = (const float4*)embed + (size_t)row * (E / 4);
    size_t xbase = (size_t)t * (E / 4) * B + b;
#pragma unroll
    for (int kk = 0; kk < 16; ++kk) {
        int e4 = half * 16 + kk;
        X4[xbase + (size_t)e4 * B] = er[e4];
    }
}

// WUt[j][s] : s<128 -> W[s][j], else U[s-128][j]
__global__ void make_wut(const float* __restrict__ W, const float* __restrict__ U,
                         float* __restrict__ WUt) {
    int j = blockIdx.x;
    int s = threadIdx.x;             // 384
    float v = (s < E) ? W[(size_t)s * 1024 + j] : U[(size_t)(s - E) * 1024 + j];
    WUt[(size_t)j * 384 + s] = v;
}

__device__ __forceinline__ float sigm(float x) { return 1.f / (1.f + __expf(-x)); }

// Persistent LSTM (EXACT R4 structure; probs removed, HS store added).
// grid = 256 (cooperative), block = 512. wg = g*8+q. Group g: batch els [4g,4g+4).
// wg q: units [32q,32q+32), all 4 gates. Thread: tid = ks*128 + oi.
__launch_bounds__(512, 2)
__global__ void lstm_persist(const float4* __restrict__ Xg, const float* __restrict__ WUt,
                             const float* __restrict__ bias, float* __restrict__ out,
                             float* __restrict__ HX, float* __restrict__ HS,
                             int* __restrict__ sync) {
    __shared__ float act[ELS][E + R];          // [4][384]: x | h
    __shared__ float partial[4][ELS][OUTS];    // [ks][el][oi]

    const int tid  = threadIdx.x;
    const int wg   = blockIdx.x;
    const int g    = wg >> 3;
    const int q    = wg & 7;
    const int lane = tid & 63;
    const int wv   = __builtin_amdgcn_readfirstlane(tid >> 6);
    const int ks   = wv >> 1;                      // 0..3 wave-uniform
    const int oi   = ((wv & 1) << 6) | lane;       // 0..127
    const int j    = (oi >> 5) * 256 + q * 32 + (oi & 31);  // weight row (gate*R + unit)

    // ---- prologue: weights -> VGPRs ----
    float4 wx[8], wh[16];
    {
        const float4* wrow = (const float4*)(WUt + (size_t)j * 384);
#pragma unroll
        for (int p = 0; p < 8; ++p)  wx[p] = wrow[8 * ks + p];
#pragma unroll
        for (int p = 0; p < 16; ++p) wh[p] = wrow[32 + 16 * ks + p];
    }

    // finisher state (tid < 128): el = tid>>5, u = tid&31
    float bias_g0 = 0.f, bias_g1 = 0.f, bias_g2 = 0.f, bias_g3 = 0.f, creg = 0.f;
    if (tid < 128) {
        int u = tid & 31;
        bias_g0 = bias[0 * 256 + q * 32 + u];
        bias_g1 = bias[1 * 256 + q * 32 + u];
        bias_g2 = bias[2 * 256 + q * 32 + u];
        bias_g3 = bias[3 * 256 + q * 32 + u];
    }

    // zero act h-part; load x_0 into act x-part
    for (int i = tid; i < ELS * (E + R); i += 512) ((float*)act)[i] = 0.f;
    __syncthreads();
    if (tid < 256) {
        int el = tid >> 6, e2 = (tid & 63) * 2;
        const float* xsrc = (const float*)(Xg + (size_t)0 * (E / 4) * B);
        // Xg float4 layout: [e4][b]; read elementwise pair: e2 = 2*(lane) within el row
        // reconstruct: element e of batch b lives at float4 (e>>2)*B + b, component e&3
        float x0 = ((const float*)&Xg[((size_t)(e2 >> 2)) * B + (4 * g + el)])[e2 & 3];
        float x1 = ((const float*)&Xg[((size_t)((e2 + 1) >> 2)) * B + (4 * g + el)])[(e2 + 1) & 3];
        act[el][e2] = x0;
        act[el][e2 + 1] = x1;
        (void)xsrc;
    }
    __syncthreads();

    int* cnt = sync + g * 32;
    int* flg = sync + g * 32 + 16;

    for (int t = 0; t < S; ++t) {
        // ---- MAC: z[oi] partial over chunk ks, all 4 els ----
        float ac0 = 0.f, ac1 = 0.f, ac2 = 0.f, ac3 = 0.f;
        {
            const int xo = 32 * ks;
#pragma unroll
            for (int p = 0; p < 8; ++p) {
                float4 w  = wx[p];
                float4 a0 = *(const float4*)&act[0][xo + 4 * p];
                float4 a1 = *(const float4*)&act[1][xo + 4 * p];
                float4 a2 = *(const float4*)&act[2][xo + 4 * p];
                float4 a3 = *(const float4*)&act[3][xo + 4 * p];
                ac0 += w.x * a0.x + w.y * a0.y + w.z * a0.z + w.w * a0.w;
                ac1 += w.x * a1.x + w.y * a1.y + w.z * a1.z + w.w * a1.w;
                ac2 += w.x * a2.x + w.y * a2.y + w.z * a2.z + w.w * a2.w;
                ac3 += w.x * a3.x + w.y * a3.y + w.z * a3.z + w.w * a3.w;
            }
            const int ho = E + 64 * ks;
#pragma unroll
            for (int p = 0; p < 16; ++p) {
                float4 w  = wh[p];
                float4 a0 = *(const float4*)&act[0][ho + 4 * p];
                float4 a1 = *(const float4*)&act[1][ho + 4 * p];
                float4 a2 = *(const float4*)&act[2][ho + 4 * p];
                float4 a3 = *(const float4*)&act[3][ho + 4 * p];
                ac0 += w.x * a0.x + w.y * a0.y + w.z * a0.z + w.w * a0.w;
                ac1 += w.x * a1.x + w.y * a1.y + w.z * a1.z + w.w * a1.w;
                ac2 += w.x * a2.x + w.y * a2.y + w.z * a2.z + w.w * a2.w;
                ac3 += w.x * a3.x + w.y * a3.y + w.z * a3.z + w.w * a3.w;
            }
        }
        partial[ks][0][oi] = ac0;
        partial[ks][1][oi] = ac1;
        partial[ks][2][oi] = ac2;
        partial[ks][3][oi] = ac3;
        __syncthreads();  // #1

        // ---- finish: gates, c/h update, HS store, coherent HX store ----
        if (tid < 128) {
            int el = tid >> 5, u = tid & 31;
            float z0 = bias_g0, z1 = bias_g1, z2 = bias_g2, z3 = bias_g3;
#pragma unroll
            for (int kk = 0; kk < 4; ++kk) {
                z0 += partial[kk][el][0 * 32 + u];
                z1 += partial[kk][el][1 * 32 + u];
                z2 += partial[kk][el][2 * 32 + u];
                z3 += partial[kk][el][3 * 32 + u];
            }
            float ig = sigm(z0), fg = sigm(z1), gv = tanhf(z2), og = sigm(z3);
            creg = fg * creg + ig * gv;
            float h = og * tanhf(creg);
            int brow = 4 * g + el, rr = q * 32 + u;
            HS[(size_t)t * B * R + (size_t)brow * R + rr] = h;   // write-once history
            float* haddr = HX + ((size_t)(t & 1) * B + brow) * R + rr;
            asm volatile("global_store_dword %0, %1, off sc0 sc1" :: "v"(haddr), "v"(h) : "memory");
            if (t == S - 1) {
                out[HOUT_OFF + (size_t)brow * R + rr] = h;
                out[COUT_OFF + (size_t)brow * R + rr] = creg;
            }
        }
        // prefetch x_{t+1} into regs (normal cached loads)
        v2f xpre;
        const bool do_x = (tid < 256) && (t < S - 1);
        if (do_x) {
            int el = tid >> 6, e2 = (tid & 63) * 2;
            xpre.x = ((const float*)&Xg[(size_t)(t + 1) * (E / 4) * B
                                        + ((size_t)(e2 >> 2)) * B + (4 * g + el)])[e2 & 3];
            xpre.y = ((const float*)&Xg[(size_t)(t + 1) * (E / 4) * B
                                        + ((size_t)((e2 + 1) >> 2)) * B + (4 * g + el)])[(e2 + 1) & 3];
        }
        asm volatile("s_waitcnt vmcnt(0)" ::: "memory");
        __syncthreads();  // #2

        // ---- group barrier (8 wgs) ----
        if (tid == 0) {
            int epoch = t + 1;
            int old = __hip_atomic_fetch_add(cnt, 1, __ATOMIC_ACQ_REL, __HIP_MEMORY_SCOPE_AGENT);
            if (old == QW - 1) {
                __hip_atomic_store(cnt, 0, __ATOMIC_RELAXED, __HIP_MEMORY_SCOPE_AGENT);
                __hip_atomic_store(flg, epoch, __ATOMIC_RELEASE, __HIP_MEMORY_SCOPE_AGENT);
            } else {
                int it = 0;
                while (__hip_atomic_load(flg, __ATOMIC_RELAXED, __HIP_MEMORY_SCOPE_AGENT) < epoch
                       && ++it < (1 << 16)) {}
            }
        }
        __syncthreads();  // #3

        // ---- pull h_t (coherent) + write act for next step ----
        {
            int el = tid >> 7, r2 = (tid & 127) * 2;
            const float* hsrc = HX + ((size_t)(t & 1) * B + 4 * g + el) * R + r2;
            v2f hv;
            asm volatile("global_load_dwordx2 %0, %1, off sc0 sc1\n\t"
                         "s_waitcnt vmcnt(0)"
                         : "=&v"(hv) : "v"(hsrc) : "memory");
            *(v2f*)&act[el][E + r2] = hv;
        }
        if (do_x) {
            int el = tid >> 6, e2 = (tid & 63) * 2;
            *(v2f*)&act[el][e2] = xpre;
        }
        __syncthreads();  // #4
    }
}

// probs[b][t][c] = softmax(h_t @ Wout + bout); HS slot t = h_t. grid (S,2) x 64.
__global__ void out_probs(const float* __restrict__ HS, const float* __restrict__ Wout,
                          const float* __restrict__ bout, float* __restrict__ out) {
    __shared__ float woutT[9][260];
    int t    = blockIdx.x;
    int bg   = blockIdx.y;
    int lane = threadIdx.x;          // 64
    int b    = bg * 64 + lane;
    for (int i = lane; i < 9 * 256; i += 64)
        woutT[i >> 8][i & 255] = Wout[(size_t)(i & 255) * 9 + (i >> 8)];
    __syncthreads();
    float acc[9];
#pragma unroll
    for (int c = 0; c < 9; ++c) acc[c] = bout[c];
    const float4* hrow = (const float4*)(HS + (size_t)t * B * R + (size_t)b * R);
#pragma unroll 8
    for (int r4 = 0; r4 < 64; ++r4) {
        float4 hv = hrow[r4];
#pragma unroll
        for (int c = 0; c < 9; ++c) {
            float4 wv = *(const float4*)&woutT[c][4 * r4];
            acc[c] += hv.x * wv.x + hv.y * wv.y + hv.z * wv.z + hv.w * wv.w;
        }
    }
    float m = acc[0];
#pragma unroll
    for (int c = 1; c < 9; ++c) m = fmaxf(m, acc[c]);
    float e[9], sum = 0.f;
#pragma unroll
    for (int c = 0; c < 9; ++c) { e[c] = __expf(acc[c] - m); sum += e[c]; }
    float inv = 1.f / sum;
#pragma unroll
    for (int c = 0; c < 9; ++c) out[((size_t)b * S + t) * 9 + c] = e[c] * inv;
}

extern "C" void kernel_launch(void* const* d_in, const int* in_sizes, int n_in,
                              void* d_out, int out_size, void* d_ws, size_t ws_size,
                              hipStream_t stream) {
    const int*   idx   = (const int*)d_in[0];
    const float* embed = (const float*)d_in[1];
    const float* W     = (const float*)d_in[2];
    const float* U     = (const float*)d_in[3];
    const float* bias  = (const float*)d_in[4];
    const float* Wout  = (const float*)d_in[5];
    const float* bout  = (const float*)d_in[6];
    float*       outp  = (float*)d_out;
    float*       ws    = (float*)d_ws;

    if (ws_size < WS_FLOATS * sizeof(float)) return;

    float*  HX   = ws + HX_OFF;
    int*    sy   = (int*)(ws + SYNC_OFF);
    float4* Xg   = (float4*)(ws + XG_OFF);
    float*  HS   = ws + HS_OFF;
    float*  WUt  = ws + WUT_OFF;

    zero_sync<<<1, 1024, 0, stream>>>(sy);
    gather_x<<<S, 256, 0, stream>>>(idx, embed, Xg);
    make_wut<<<1024, 384, 0, stream>>>(W, U, WUt);

    void* args[] = {(void*)&Xg, (void*)&WUt, (void*)&bias, (void*)&outp,
                    (void*)&HX, (void*)&HS, (void*)&sy};
    (void)hipLaunchCooperativeKernel((const void*)lstm_persist, dim3(256), dim3(512),
                                     args, 0, stream);

    out_probs<<<dim3(S, 2), 64, 0, stream>>>(HS, Wout, bout, outp);
}